// Round 8
// baseline (2556.029 us; speedup 1.0000x reference)
//
#include <hip/hip_runtime.h>
#include <hip/hip_bf16.h>

// LSMPool round 8: widen the fc1 wave tile to cut the LDS-read pipe term.
//   Round-7 post-mortem: per-CU cost ≈ max(LDS reads 4.8us, w1 L3-stream
//   ~5-6us) — wave tile m4n1 has reads/MFMA=0.75. New tile m4n2 (wave=64x32):
//   reads/MFMA=0.5 -> 640 ds_read_b128/CU ≈ 3.2us, hidden under w1 stream.
//   k_fc1: block = M64 x N128, KSPL=8 (KRANGE=640, NWIN=10), grid 32x8=256.
//     LDS/window 40KB (A 8K | Bh 16K | Bl 16K), depth-3 = 120KB.
//     40 slabs/window (10 gload_lds16 per wave), counted vmcnt(10) +
//     raw s_barrier (round-7-proven pattern). Pre-swizzled source chunks.
//   k_fc1_red: 8-way partial reduce (fixed order) + LIF + spike bits.
//   part aliases cur2 (disjoint lifetimes) to keep ws at round-2 levels.
//   prep / ro_gemm v2 / ro_scan unchanged.

namespace {
constexpr int T_STEPS = 128;
constexpr int BATCH   = 64;
constexpr int IN_F    = 1024;
constexpr int HID     = 4096;
constexpr int OUT_F   = 512;
constexpr int TOTAL   = IN_F + HID;    // 5120
constexpr int BK      = 64;
constexpr int NCH     = 32;            // n-chunks of 128
constexpr int KSPL    = 8;
constexpr int KRANGE  = TOTAL / KSPL;  // 640
constexpr int NWIN    = KRANGE / BK;   // 10
constexpr int BUFB    = 40960;         // A 8K | Bh 16K | Bl 16K
constexpr int NBUF    = 3;             // 122880 B LDS
}

using bf16x8 = __attribute__((ext_vector_type(8))) short;
using f32x4  = __attribute__((ext_vector_type(4))) float;

__device__ __forceinline__ void gload_lds16(const void* g, void* l) {
  __builtin_amdgcn_global_load_lds(
      (const __attribute__((address_space(1))) unsigned int*)(g),
      (__attribute__((address_space(3))) unsigned int*)(l), 16, 0, 0);
}

// ---------------- prep kernels ----------------

__global__ void k_cvt_split(const float* __restrict__ src,
                            __hip_bfloat16* __restrict__ hi,
                            __hip_bfloat16* __restrict__ lo, int n4) {
  int i = blockIdx.x * blockDim.x + threadIdx.x;
  if (i >= n4) return;
  float4 v = reinterpret_cast<const float4*>(src)[i];
#define CVT1(J, F)                                                        \
  {                                                                       \
    __hip_bfloat16 hb = __float2bfloat16(F);                              \
    hi[4 * (size_t)i + J] = hb;                                           \
    lo[4 * (size_t)i + J] = __float2bfloat16((F) - __bfloat162float(hb)); \
  }
  CVT1(0, v.x) CVT1(1, v.y) CVT1(2, v.z) CVT1(3, v.w)
#undef CVT1
}

__global__ void k_cvt_x(const float* __restrict__ src,
                        __hip_bfloat16* __restrict__ dst, int n) {
  int i = blockIdx.x * blockDim.x + threadIdx.x;
  if (i >= n) return;
  dst[i] = __float2bfloat16(src[i]);
}

__global__ void k_zero(float* __restrict__ mem1, ushort* __restrict__ spk0, int n) {
  int i = blockIdx.x * blockDim.x + threadIdx.x;
  if (i >= n) return;
  mem1[i] = 0.0f;
  spk0[i] = 0;  // bf16 +0.0
}

// ---------------- fc1 K-split GEMM (wave tile 64x32) ----------------
// block = (nchunk = blockIdx&31 -> N=128, ks = blockIdx>>5 -> K=640).
// wave wv owns n-cols [wv*32, wv*32+32) (2 n-frags) x all 64 batch rows.
// LDS window: A[64][64] @0 | Bh[128][64] @8192 | Bl[128][64] @24576, bf16,
// rows 128 B; 16B-chunk c of row r stored at chunk (c ^ (r&7)).
__global__ __launch_bounds__(256, 1)
void k_fc1(int t,
           const __hip_bfloat16* __restrict__ xb,    // [T][B][IN_F]
           const __hip_bfloat16* __restrict__ spk,   // [T+1][B][HID]
           const __hip_bfloat16* __restrict__ w1hi,  // [HID][TOTAL]
           const __hip_bfloat16* __restrict__ w1lo,
           float* __restrict__ part) {               // [KSPL][B][HID]
  __shared__ __align__(16) char smem[NBUF * BUFB];

  const int tid = threadIdx.x;
  const int l   = tid & 63;
  const int wv  = tid >> 6;
  const int nchunk = blockIdx.x & (NCH - 1);
  const int ks     = blockIdx.x >> 5;
  const int nbase  = nchunk * 128;
  const int kbase  = ks * KRANGE;

  const __hip_bfloat16* xbt  = xb  + (size_t)t * BATCH * IN_F;
  const __hip_bfloat16* spkt = spk + (size_t)t * BATCH * HID;

  // staging: slab = 8 rows x 64 cols (1KB). slabs 0..7 = A, 8..23 = Bh,
  // 24..39 = Bl; wave wv stages slabs [10wv, 10wv+10).
  const int row8 = l >> 3;                  // row within slab
  const int cswz = ((l & 7) ^ row8) * 8;    // pre-swizzled source chunk (elems)

  // fragment geometry
  const int fr  = l & 15;                   // fragment row
  const int fks = l >> 4;                   // 16B chunk-in-ksub 0..3
  const int f7  = fr & 7;

  f32x4 acc[4][2];
#pragma unroll
  for (int mf = 0; mf < 4; ++mf)
#pragma unroll
    for (int nf = 0; nf < 2; ++nf) acc[mf][nf] = (f32x4){0.f, 0.f, 0.f, 0.f};

  auto ISSUE = [&](int iw, char* buf) {
    const int k0 = kbase + iw * BK;         // windows never straddle x/spk
    const bool isX = (k0 < IN_F);
    const __hip_bfloat16* aBase = isX ? (xbt + k0) : (spkt + (k0 - IN_F));
    const int aStride = isX ? IN_F : HID;
#pragma unroll
    for (int u = 0; u < 10; ++u) {
      const int s2 = wv * 10 + u;
      if (s2 < 8) {
        gload_lds16(aBase + (size_t)(s2 * 8 + row8) * aStride + cswz,
                    buf + s2 * 1024);
      } else if (s2 < 24) {
        const int j = s2 - 8;
        gload_lds16(w1hi + (size_t)(nbase + j * 8 + row8) * TOTAL + k0 + cswz,
                    buf + 8192 + j * 1024);
      } else {
        const int j = s2 - 24;
        gload_lds16(w1lo + (size_t)(nbase + j * 8 + row8) * TOTAL + k0 + cswz,
                    buf + 24576 + j * 1024);
      }
    }
  };

  auto COMP = [&](const char* buf) {
    const int rB0 = (wv * 32 + fr) * 128;
    const int rB1 = (wv * 32 + 16 + fr) * 128;
#pragma unroll
    for (int s = 0; s < 2; ++s) {
      const int co = ((s * 4 + fks) ^ f7) * 16;
      bf16x8 bh0 = *(const bf16x8*)(buf + 8192  + rB0 + co);
      bf16x8 bl0 = *(const bf16x8*)(buf + 24576 + rB0 + co);
      bf16x8 bh1 = *(const bf16x8*)(buf + 8192  + rB1 + co);
      bf16x8 bl1 = *(const bf16x8*)(buf + 24576 + rB1 + co);
#pragma unroll
      for (int mf = 0; mf < 4; ++mf) {
        bf16x8 a = *(const bf16x8*)(buf + (mf * 16 + fr) * 128 + co);
        acc[mf][0] = __builtin_amdgcn_mfma_f32_16x16x32_bf16(a, bh0, acc[mf][0], 0, 0, 0);
        acc[mf][0] = __builtin_amdgcn_mfma_f32_16x16x32_bf16(a, bl0, acc[mf][0], 0, 0, 0);
        acc[mf][1] = __builtin_amdgcn_mfma_f32_16x16x32_bf16(a, bh1, acc[mf][1], 0, 0, 0);
        acc[mf][1] = __builtin_amdgcn_mfma_f32_16x16x32_bf16(a, bl1, acc[mf][1], 0, 0, 0);
      }
    }
  };

  // depth-3 pipeline: counted vmcnt (never 0 mid-loop) + raw s_barrier.
  ISSUE(0, smem);
  ISSUE(1, smem + BUFB);
  for (int i = 0; i < NWIN; ++i) {
    if (i + 1 < NWIN) {
      asm volatile("s_waitcnt vmcnt(10)" ::: "memory");  // window i landed
    } else {
      asm volatile("s_waitcnt vmcnt(0)" ::: "memory");   // last window
    }
    __builtin_amdgcn_s_barrier();          // all waves' window-i loads visible
    asm volatile("" ::: "memory");
    const char* bufc = smem + (i % 3) * BUFB;
    COMP(bufc);
    if (i + 2 < NWIN) ISSUE(i + 2, smem + ((i + 2) % 3) * BUFB);
  }

  // write K-split partials. C/D: col(lane&15)=n, row=(lane>>4)*4+q=batch.
  const int brow = (l >> 4) * 4;
#pragma unroll
  for (int nf = 0; nf < 2; ++nf) {
    float* pp = part + (size_t)ks * (BATCH * HID) + nbase + wv * 32 + nf * 16 + fr;
#pragma unroll
    for (int mf = 0; mf < 4; ++mf) {
#pragma unroll
      for (int q = 0; q < 4; ++q) {
        pp[(size_t)(mf * 16 + brow + q) * HID] = acc[mf][nf][q];
      }
    }
  }
}

// ---------------- fc1 partial-reduce + LIF (fused) ----------------
// 256 blocks x 256 thr x 4 elems = 262144 = B*HID. Fixed ks order.
// Spikes are exactly 0.0/1.0 -> write bf16 bit patterns 0x0000/0x3F80.
__global__ __launch_bounds__(256)
void k_fc1_red(const float* __restrict__ part,   // [KSPL][B][HID]
               float* __restrict__ mem1,         // [B][HID]
               const float* __restrict__ beta,   // [HID]
               const float* __restrict__ thr,    // [HID]
               ushort* __restrict__ spk_out) {   // [B][HID] bf16 bits
  const int i0 = (blockIdx.x * 256 + threadIdx.x) * 4;
  constexpr int PS = BATCH * HID;  // 262144
  float4 c = *(const float4*)(part + i0);
#pragma unroll
  for (int k2 = 1; k2 < KSPL; ++k2) {
    const float4 p = *(const float4*)(part + (size_t)k2 * PS + i0);
    c.x += p.x; c.y += p.y; c.z += p.z; c.w += p.w;
  }

  const int n0 = i0 & (HID - 1);
  const float4 bt = *(const float4*)(beta + n0);
  const float4 th = *(const float4*)(thr + n0);
  float4 mv = *(float4*)(mem1 + i0);

  ushort4 so;
#define LIF1(COMP_M, COMP_B, COMP_T, SOUT)                  \
  {                                                         \
    float m2 = COMP_M - COMP_B + c.SOUT;                    \
    m2 = fmaxf(m2, 0.f);                                    \
    const bool sp = (m2 > COMP_T);                          \
    if (sp) m2 -= COMP_T;                                   \
    COMP_M = m2;                                            \
    so.SOUT = sp ? (ushort)0x3F80 : (ushort)0;              \
  }
  LIF1(mv.x, bt.x, th.x, x)
  LIF1(mv.y, bt.y, th.y, y)
  LIF1(mv.z, bt.z, th.z, z)
  LIF1(mv.w, bt.w, th.w, w)
#undef LIF1
  *(float4*)(mem1 + i0) = mv;
  *(ushort4*)(spk_out + i0) = so;
}

// ---------------- readout GEMM v2 (unchanged) ----------------
__global__ __launch_bounds__(256, 2)
void k_ro_gemm(const __hip_bfloat16* __restrict__ A,
               const __hip_bfloat16* __restrict__ w2hi,
               const __hip_bfloat16* __restrict__ w2lo,
               const float* __restrict__ b2,
               float* __restrict__ cur2) {
  __shared__ __align__(16) short lA[2][64 * BK];
  __shared__ __align__(16) short lBh[2][64 * BK];
  __shared__ __align__(16) short lBl[2][64 * BK];

  const int tid  = threadIdx.x;
  const int lane = tid & 63;
  const int w    = tid >> 6;

  const int xcd = blockIdx.x & 7;
  const int c   = blockIdx.x >> 3;
  const int mt  = xcd * 16 + (c >> 3);
  const int nt  = c & 7;
  const int mbase = mt * 64;
  const int nbase = nt * 64;

  const int rS   = tid >> 2;
  const int cEl  = (tid & 3) * 16;
  const int swzX = (rS & 7) << 4;
  const int stByte0 = rS * 128 + ((cEl * 2) ^ swzX);
  const int stByte1 = rS * 128 + ((cEl * 2 + 16) ^ swzX);

  const int fr    = lane & 15;
  const int fkB   = (lane >> 4) * 16;
  const int frSwz = (fr & 7) << 4;

  f32x4 acc[4];
#pragma unroll
  for (int m = 0; m < 4; ++m) acc[m] = (f32x4){0.f, 0.f, 0.f, 0.f};
  bf16x8 rgA[6], rgB[6];

  auto GLOAD = [&](int it, bf16x8* R) {
    const int k0 = it * BK;
    const __hip_bfloat16* asrc = A    + (size_t)(mbase + rS) * HID + k0 + cEl;
    const __hip_bfloat16* hsrc = w2hi + (size_t)(nbase + rS) * HID + k0 + cEl;
    const __hip_bfloat16* lsrc = w2lo + (size_t)(nbase + rS) * HID + k0 + cEl;
    R[0] = *(const bf16x8*)(asrc);
    R[1] = *(const bf16x8*)(asrc + 8);
    R[2] = *(const bf16x8*)(hsrc);
    R[3] = *(const bf16x8*)(hsrc + 8);
    R[4] = *(const bf16x8*)(lsrc);
    R[5] = *(const bf16x8*)(lsrc + 8);
  };
  auto DSWRITE = [&](int ibuf, bf16x8* R) {
    *(bf16x8*)((char*)lA[ibuf] + stByte0)  = R[0];
    *(bf16x8*)((char*)lA[ibuf] + stByte1)  = R[1];
    *(bf16x8*)((char*)lBh[ibuf] + stByte0) = R[2];
    *(bf16x8*)((char*)lBh[ibuf] + stByte1) = R[3];
    *(bf16x8*)((char*)lBl[ibuf] + stByte0) = R[4];
    *(bf16x8*)((char*)lBl[ibuf] + stByte1) = R[5];
  };
  auto COMPUTE = [&](int ibuf) {
    const char* pA  = (const char*)lA[ibuf];
    const char* pBh = (const char*)lBh[ibuf];
    const char* pBl = (const char*)lBl[ibuf];
#pragma unroll
    for (int s = 0; s < 2; ++s) {
      const int co = ((s * 64 + fkB) ^ frSwz);
      bf16x8 fbh = *(const bf16x8*)(pBh + (w * 16 + fr) * 128 + co);
      bf16x8 fbl = *(const bf16x8*)(pBl + (w * 16 + fr) * 128 + co);
#pragma unroll
      for (int m = 0; m < 4; ++m) {
        bf16x8 fa = *(const bf16x8*)(pA + (m * 16 + fr) * 128 + co);
        acc[m] = __builtin_amdgcn_mfma_f32_16x16x32_bf16(fa, fbh, acc[m], 0, 0, 0);
        acc[m] = __builtin_amdgcn_mfma_f32_16x16x32_bf16(fa, fbl, acc[m], 0, 0, 0);
      }
    }
  };

  constexpr int RNIT = HID / BK;  // 64
  GLOAD(0, rgA);
  DSWRITE(0, rgA);
  __syncthreads();
  for (int itp = 0; itp < RNIT / 2; ++itp) {
    const int it = itp * 2;
    GLOAD(it + 1, rgB);
    COMPUTE(0);
    DSWRITE(1, rgB);
    __syncthreads();
    if (it + 2 < RNIT) {
      GLOAD(it + 2, rgA);
      COMPUTE(1);
      DSWRITE(0, rgA);
      __syncthreads();
    } else {
      COMPUTE(1);
    }
  }

  const int col = nbase + w * 16 + fr;
  const float bias = b2[col];
  const int brow = (lane >> 4) * 4;
#pragma unroll
  for (int m = 0; m < 4; ++m) {
#pragma unroll
    for (int q = 0; q < 4; ++q) {
      const int row = mbase + m * 16 + brow + q;
      cur2[(size_t)row * OUT_F + col] = acc[m][q] + bias;
    }
  }
}

// ---------------- readout LIF scan ----------------
__global__ void k_ro_scan(const float* __restrict__ cur2,
                          const float* __restrict__ beta,
                          const float* __restrict__ thr,
                          float* __restrict__ out) {
  const int i = blockIdx.x * blockDim.x + threadIdx.x;
  const int b = i >> 9;
  const int o = i & (OUT_F - 1);
  const float bt = beta[o];
  const float th = thr[o];
  float m = 0.0f;
  for (int t = 0; t < T_STEPS; ++t) {
    const size_t idx = (size_t)(t * BATCH + b) * OUT_F + o;
    m = m - bt + cur2[idx];
    const float s = (m > th) ? 1.0f : 0.0f;
    m -= s * th;
    out[idx] = s;
  }
}

// ---------------- launch ----------------
extern "C" void kernel_launch(void* const* d_in, const int* in_sizes, int n_in,
                              void* d_out, int out_size, void* d_ws, size_t ws_size,
                              hipStream_t stream) {
  const float* x        = (const float*)d_in[0];
  const float* w1       = (const float*)d_in[1];
  const float* w2       = (const float*)d_in[2];
  const float* b2       = (const float*)d_in[3];
  const float* beta_lsm = (const float*)d_in[4];
  const float* thr_lsm  = (const float*)d_in[5];
  const float* beta_ro  = (const float*)d_in[6];
  const float* thr_ro   = (const float*)d_in[7];
  float* out = (float*)d_out;

  char* ws = (char*)d_ws;
  size_t off = 0;
  auto alloc = [&](size_t bytes) -> char* {
    char* p = ws + off;
    off += (bytes + 255) & ~(size_t)255;
    return p;
  };
  __hip_bfloat16* w1hi = (__hip_bfloat16*)alloc((size_t)HID * TOTAL * 2);
  __hip_bfloat16* w1lo = (__hip_bfloat16*)alloc((size_t)HID * TOTAL * 2);
  __hip_bfloat16* xb   = (__hip_bfloat16*)alloc((size_t)T_STEPS * BATCH * IN_F * 2);
  __hip_bfloat16* spk  = (__hip_bfloat16*)alloc((size_t)(T_STEPS + 1) * BATCH * HID * 2);
  __hip_bfloat16* w2hi = (__hip_bfloat16*)alloc((size_t)OUT_F * HID * 2);
  __hip_bfloat16* w2lo = (__hip_bfloat16*)alloc((size_t)OUT_F * HID * 2);
  float* mem1 = (float*)alloc((size_t)BATCH * HID * 4);
  // part ([KSPL][B][HID] f32, 8MB) aliases cur2 (16.8MB): disjoint lifetimes
  // (part: step phase only; cur2: readout phase only).
  float* cur2 = (float*)alloc((size_t)T_STEPS * BATCH * OUT_F * 4);
  float* part = cur2;

  // prep
  {
    int n4 = HID * TOTAL / 4;
    k_cvt_split<<<(n4 + 255) / 256, 256, 0, stream>>>(w1, w1hi, w1lo, n4);
  }
  {
    int n4 = OUT_F * HID / 4;
    k_cvt_split<<<(n4 + 255) / 256, 256, 0, stream>>>(w2, w2hi, w2lo, n4);
  }
  {
    int n = T_STEPS * BATCH * IN_F;
    k_cvt_x<<<(n + 255) / 256, 256, 0, stream>>>(x, xb, n);
  }
  {
    int n = BATCH * HID;
    k_zero<<<(n + 255) / 256, 256, 0, stream>>>(mem1, (ushort*)spk, n);
  }

  // sequential reservoir steps: K-split GEMM + fused reduce/LIF per step
  for (int t = 0; t < T_STEPS; ++t) {
    k_fc1<<<NCH * KSPL, 256, 0, stream>>>(t, xb, spk, w1hi, w1lo, part);
    k_fc1_red<<<BATCH * HID / (256 * 4), 256, 0, stream>>>(
        part, mem1, beta_lsm, thr_lsm,
        (ushort*)(spk + (size_t)(t + 1) * BATCH * HID));
  }

  // readout
  k_ro_gemm<<<(T_STEPS * BATCH / 64) * (OUT_F / 64), 256, 0, stream>>>(
      spk + (size_t)BATCH * HID, w2hi, w2lo, b2, cur2);
  k_ro_scan<<<(BATCH * OUT_F) / 256, 256, 0, stream>>>(cur2, beta_ro, thr_ro, out);
}

// Round 9
// 2517.354 us; speedup vs baseline: 1.0154x; 1.0154x over previous
//
#include <hip/hip_runtime.h>
#include <hip/hip_bf16.h>

// LSMPool round 9: cross-block TLP for the step GEMM.
//   Rounds 3/7/8 all ~17us/step despite different tiles -> not pipe-bound;
//   all ran 1 block/CU with barrier-coupled pipelines (stalls serialize).
//   k_fc1 v3: round-7 geometry (N=64, 6 gloads/wave/window, vmcnt(6),
//   depth-3, raw s_barrier) but KSPL=8 -> grid 64x8=512 = 2 blocks/CU
//   (LDS 72KB*2=144 <= 160KB), __launch_bounds__(256,2). Block B computes
//   while block A waits -> stall terms overlap.
//   k_fc1_red: KSPL=8 reduce + LIF + spike bits (round-8 version).
//   part aliases cur2. prep / ro_gemm v2 / ro_scan unchanged.

namespace {
constexpr int T_STEPS = 128;
constexpr int BATCH   = 64;
constexpr int IN_F    = 1024;
constexpr int HID     = 4096;
constexpr int OUT_F   = 512;
constexpr int TOTAL   = IN_F + HID;    // 5120
constexpr int BK      = 64;
constexpr int NCH     = 64;            // n-chunks of 64
constexpr int KSPL    = 8;
constexpr int KRANGE  = TOTAL / KSPL;  // 640
constexpr int NWIN    = KRANGE / BK;   // 10
constexpr int BUFB    = 24576;         // A 8K | Bh 8K | Bl 8K
constexpr int NBUF    = 3;             // 73728 B LDS (2 blocks/CU = 144K)
}

using bf16x8 = __attribute__((ext_vector_type(8))) short;
using f32x4  = __attribute__((ext_vector_type(4))) float;

__device__ __forceinline__ void gload_lds16(const void* g, void* l) {
  __builtin_amdgcn_global_load_lds(
      (const __attribute__((address_space(1))) unsigned int*)(g),
      (__attribute__((address_space(3))) unsigned int*)(l), 16, 0, 0);
}

// ---------------- prep kernels ----------------

__global__ void k_cvt_split(const float* __restrict__ src,
                            __hip_bfloat16* __restrict__ hi,
                            __hip_bfloat16* __restrict__ lo, int n4) {
  int i = blockIdx.x * blockDim.x + threadIdx.x;
  if (i >= n4) return;
  float4 v = reinterpret_cast<const float4*>(src)[i];
#define CVT1(J, F)                                                        \
  {                                                                       \
    __hip_bfloat16 hb = __float2bfloat16(F);                              \
    hi[4 * (size_t)i + J] = hb;                                           \
    lo[4 * (size_t)i + J] = __float2bfloat16((F) - __bfloat162float(hb)); \
  }
  CVT1(0, v.x) CVT1(1, v.y) CVT1(2, v.z) CVT1(3, v.w)
#undef CVT1
}

__global__ void k_cvt_x(const float* __restrict__ src,
                        __hip_bfloat16* __restrict__ dst, int n) {
  int i = blockIdx.x * blockDim.x + threadIdx.x;
  if (i >= n) return;
  dst[i] = __float2bfloat16(src[i]);
}

__global__ void k_zero(float* __restrict__ mem1, ushort* __restrict__ spk0, int n) {
  int i = blockIdx.x * blockDim.x + threadIdx.x;
  if (i >= n) return;
  mem1[i] = 0.0f;
  spk0[i] = 0;  // bf16 +0.0
}

// ---------------- fc1 K-split GEMM (2 blocks/CU) ----------------
// block = (nchunk = blockIdx&63 -> N=64, ks = blockIdx>>6 -> K=640).
// 4 waves: wave wv computes n-sub [wv*16, wv*16+16) for all 64 batch rows.
// Staged window: A[64][64] @0 | Bh[64][64] @8192 | Bl[64][64] @16384 bf16,
// rows 128 B; 16B-chunk c of row r stored at chunk (c ^ (r&7)) [src-preswz].
__global__ __launch_bounds__(256, 2)
void k_fc1(int t,
           const __hip_bfloat16* __restrict__ xb,    // [T][B][IN_F]
           const __hip_bfloat16* __restrict__ spk,   // [T+1][B][HID]
           const __hip_bfloat16* __restrict__ w1hi,  // [HID][TOTAL]
           const __hip_bfloat16* __restrict__ w1lo,
           float* __restrict__ part) {               // [KSPL][B][HID]
  __shared__ __align__(16) char smem[NBUF * BUFB];

  const int tid = threadIdx.x;
  const int l   = tid & 63;
  const int wv  = tid >> 6;
  const int nchunk = blockIdx.x & 63;
  const int ks     = blockIdx.x >> 6;
  const int nbase  = nchunk * 64;
  const int kbase  = ks * KRANGE;

  const __hip_bfloat16* xbt  = xb  + (size_t)t * BATCH * IN_F;
  const __hip_bfloat16* spkt = spk + (size_t)t * BATCH * HID;

  // staging: one gload_lds16 per wave = one 8-row x 64-col slab (1KB).
  // wave wv stages slabs {2wv, 2wv+1} of each of A / Bh / Bl (6 loads/wave).
  const int row8 = l >> 3;                  // row within slab
  const int cswz = ((l & 7) ^ row8) * 8;    // pre-swizzled chunk (elem offset)
  const int s0 = 2 * wv, s1 = 2 * wv + 1;
  const int rA0 = s0 * 8 + row8;            // tile rows staged by this lane
  const int rA1 = s1 * 8 + row8;

  // fragment geometry
  const int fr  = l & 15;
  const int fks = l >> 4;                   // chunk-in-ksub 0..3
  const int f7  = fr & 7;

  f32x4 acc[4];
#pragma unroll
  for (int mf = 0; mf < 4; ++mf) acc[mf] = (f32x4){0.f, 0.f, 0.f, 0.f};

  auto ISSUE = [&](int iw, char* buf) {
    const int k0 = kbase + iw * BK;         // windows never straddle x/spk
    if (k0 < IN_F) {
      gload_lds16(xbt + (size_t)rA0 * IN_F + k0 + cswz, buf + s0 * 1024);
      gload_lds16(xbt + (size_t)rA1 * IN_F + k0 + cswz, buf + s1 * 1024);
    } else {
      const int kh = k0 - IN_F;
      gload_lds16(spkt + (size_t)rA0 * HID + kh + cswz, buf + s0 * 1024);
      gload_lds16(spkt + (size_t)rA1 * HID + kh + cswz, buf + s1 * 1024);
    }
    gload_lds16(w1hi + (size_t)(nbase + rA0) * TOTAL + k0 + cswz,
                buf + 8192 + s0 * 1024);
    gload_lds16(w1hi + (size_t)(nbase + rA1) * TOTAL + k0 + cswz,
                buf + 8192 + s1 * 1024);
    gload_lds16(w1lo + (size_t)(nbase + rA0) * TOTAL + k0 + cswz,
                buf + 16384 + s0 * 1024);
    gload_lds16(w1lo + (size_t)(nbase + rA1) * TOTAL + k0 + cswz,
                buf + 16384 + s1 * 1024);
  };

  auto COMP = [&](const char* buf) {
    const int browB = wv * 16 + fr;
#pragma unroll
    for (int s = 0; s < 2; ++s) {
      const int co = ((s * 4 + fks) ^ f7) * 16;
      bf16x8 bh = *(const bf16x8*)(buf + 8192  + browB * 128 + co);
      bf16x8 bl = *(const bf16x8*)(buf + 16384 + browB * 128 + co);
#pragma unroll
      for (int mf = 0; mf < 4; ++mf) {
        bf16x8 a = *(const bf16x8*)(buf + (mf * 16 + fr) * 128 + co);
        acc[mf] = __builtin_amdgcn_mfma_f32_16x16x32_bf16(a, bh, acc[mf], 0, 0, 0);
        acc[mf] = __builtin_amdgcn_mfma_f32_16x16x32_bf16(a, bl, acc[mf], 0, 0, 0);
      }
    }
  };

  // depth-3 pipeline: counted vmcnt (never 0 mid-loop) + raw s_barrier.
  ISSUE(0, smem);
  ISSUE(1, smem + BUFB);
  for (int i = 0; i < NWIN; ++i) {
    if (i + 1 < NWIN) {
      asm volatile("s_waitcnt vmcnt(6)" ::: "memory");   // window i landed
    } else {
      asm volatile("s_waitcnt vmcnt(0)" ::: "memory");   // last window
    }
    __builtin_amdgcn_s_barrier();          // all waves' window-i loads visible
    asm volatile("" ::: "memory");
    const char* bufc = smem + (i % 3) * BUFB;
    COMP(bufc);
    if (i + 2 < NWIN) ISSUE(i + 2, smem + ((i + 2) % 3) * BUFB);
  }

  // write K-split partial. C/D layout: col(lane&15)=n, row=(lane>>4)*4+q=batch.
  float* pp = part + (size_t)ks * (BATCH * HID) + nbase + wv * 16 + fr;
  const int brow = (l >> 4) * 4;
#pragma unroll
  for (int mf = 0; mf < 4; ++mf) {
#pragma unroll
    for (int q = 0; q < 4; ++q) {
      pp[(size_t)(mf * 16 + brow + q) * HID] = acc[mf][q];
    }
  }
}

// ---------------- fc1 partial-reduce + LIF (fused) ----------------
// 256 blocks x 256 thr x 4 elems = 262144 = B*HID. Fixed ks order.
// Spikes are exactly 0.0/1.0 -> write bf16 bit patterns 0x0000/0x3F80.
__global__ __launch_bounds__(256)
void k_fc1_red(const float* __restrict__ part,   // [KSPL][B][HID]
               float* __restrict__ mem1,         // [B][HID]
               const float* __restrict__ beta,   // [HID]
               const float* __restrict__ thr,    // [HID]
               ushort* __restrict__ spk_out) {   // [B][HID] bf16 bits
  const int i0 = (blockIdx.x * 256 + threadIdx.x) * 4;
  constexpr int PS = BATCH * HID;  // 262144
  float4 c = *(const float4*)(part + i0);
#pragma unroll
  for (int k2 = 1; k2 < KSPL; ++k2) {
    const float4 p = *(const float4*)(part + (size_t)k2 * PS + i0);
    c.x += p.x; c.y += p.y; c.z += p.z; c.w += p.w;
  }

  const int n0 = i0 & (HID - 1);
  const float4 bt = *(const float4*)(beta + n0);
  const float4 th = *(const float4*)(thr + n0);
  float4 mv = *(float4*)(mem1 + i0);

  ushort4 so;
#define LIF1(COMP_M, COMP_B, COMP_T, SOUT)                  \
  {                                                         \
    float m2 = COMP_M - COMP_B + c.SOUT;                    \
    m2 = fmaxf(m2, 0.f);                                    \
    const bool sp = (m2 > COMP_T);                          \
    if (sp) m2 -= COMP_T;                                   \
    COMP_M = m2;                                            \
    so.SOUT = sp ? (ushort)0x3F80 : (ushort)0;              \
  }
  LIF1(mv.x, bt.x, th.x, x)
  LIF1(mv.y, bt.y, th.y, y)
  LIF1(mv.z, bt.z, th.z, z)
  LIF1(mv.w, bt.w, th.w, w)
#undef LIF1
  *(float4*)(mem1 + i0) = mv;
  *(ushort4*)(spk_out + i0) = so;
}

// ---------------- readout GEMM v2 (unchanged) ----------------
__global__ __launch_bounds__(256, 2)
void k_ro_gemm(const __hip_bfloat16* __restrict__ A,
               const __hip_bfloat16* __restrict__ w2hi,
               const __hip_bfloat16* __restrict__ w2lo,
               const float* __restrict__ b2,
               float* __restrict__ cur2) {
  __shared__ __align__(16) short lA[2][64 * BK];
  __shared__ __align__(16) short lBh[2][64 * BK];
  __shared__ __align__(16) short lBl[2][64 * BK];

  const int tid  = threadIdx.x;
  const int lane = tid & 63;
  const int w    = tid >> 6;

  const int xcd = blockIdx.x & 7;
  const int c   = blockIdx.x >> 3;
  const int mt  = xcd * 16 + (c >> 3);
  const int nt  = c & 7;
  const int mbase = mt * 64;
  const int nbase = nt * 64;

  const int rS   = tid >> 2;
  const int cEl  = (tid & 3) * 16;
  const int swzX = (rS & 7) << 4;
  const int stByte0 = rS * 128 + ((cEl * 2) ^ swzX);
  const int stByte1 = rS * 128 + ((cEl * 2 + 16) ^ swzX);

  const int fr    = lane & 15;
  const int fkB   = (lane >> 4) * 16;
  const int frSwz = (fr & 7) << 4;

  f32x4 acc[4];
#pragma unroll
  for (int m = 0; m < 4; ++m) acc[m] = (f32x4){0.f, 0.f, 0.f, 0.f};
  bf16x8 rgA[6], rgB[6];

  auto GLOAD = [&](int it, bf16x8* R) {
    const int k0 = it * BK;
    const __hip_bfloat16* asrc = A    + (size_t)(mbase + rS) * HID + k0 + cEl;
    const __hip_bfloat16* hsrc = w2hi + (size_t)(nbase + rS) * HID + k0 + cEl;
    const __hip_bfloat16* lsrc = w2lo + (size_t)(nbase + rS) * HID + k0 + cEl;
    R[0] = *(const bf16x8*)(asrc);
    R[1] = *(const bf16x8*)(asrc + 8);
    R[2] = *(const bf16x8*)(hsrc);
    R[3] = *(const bf16x8*)(hsrc + 8);
    R[4] = *(const bf16x8*)(lsrc);
    R[5] = *(const bf16x8*)(lsrc + 8);
  };
  auto DSWRITE = [&](int ibuf, bf16x8* R) {
    *(bf16x8*)((char*)lA[ibuf] + stByte0)  = R[0];
    *(bf16x8*)((char*)lA[ibuf] + stByte1)  = R[1];
    *(bf16x8*)((char*)lBh[ibuf] + stByte0) = R[2];
    *(bf16x8*)((char*)lBh[ibuf] + stByte1) = R[3];
    *(bf16x8*)((char*)lBl[ibuf] + stByte0) = R[4];
    *(bf16x8*)((char*)lBl[ibuf] + stByte1) = R[5];
  };
  auto COMPUTE = [&](int ibuf) {
    const char* pA  = (const char*)lA[ibuf];
    const char* pBh = (const char*)lBh[ibuf];
    const char* pBl = (const char*)lBl[ibuf];
#pragma unroll
    for (int s = 0; s < 2; ++s) {
      const int co = ((s * 64 + fkB) ^ frSwz);
      bf16x8 fbh = *(const bf16x8*)(pBh + (w * 16 + fr) * 128 + co);
      bf16x8 fbl = *(const bf16x8*)(pBl + (w * 16 + fr) * 128 + co);
#pragma unroll
      for (int m = 0; m < 4; ++m) {
        bf16x8 fa = *(const bf16x8*)(pA + (m * 16 + fr) * 128 + co);
        acc[m] = __builtin_amdgcn_mfma_f32_16x16x32_bf16(fa, fbh, acc[m], 0, 0, 0);
        acc[m] = __builtin_amdgcn_mfma_f32_16x16x32_bf16(fa, fbl, acc[m], 0, 0, 0);
      }
    }
  };

  constexpr int RNIT = HID / BK;  // 64
  GLOAD(0, rgA);
  DSWRITE(0, rgA);
  __syncthreads();
  for (int itp = 0; itp < RNIT / 2; ++itp) {
    const int it = itp * 2;
    GLOAD(it + 1, rgB);
    COMPUTE(0);
    DSWRITE(1, rgB);
    __syncthreads();
    if (it + 2 < RNIT) {
      GLOAD(it + 2, rgA);
      COMPUTE(1);
      DSWRITE(0, rgA);
      __syncthreads();
    } else {
      COMPUTE(1);
    }
  }

  const int col = nbase + w * 16 + fr;
  const float bias = b2[col];
  const int brow = (lane >> 4) * 4;
#pragma unroll
  for (int m = 0; m < 4; ++m) {
#pragma unroll
    for (int q = 0; q < 4; ++q) {
      const int row = mbase + m * 16 + brow + q;
      cur2[(size_t)row * OUT_F + col] = acc[m][q] + bias;
    }
  }
}

// ---------------- readout LIF scan ----------------
__global__ void k_ro_scan(const float* __restrict__ cur2,
                          const float* __restrict__ beta,
                          const float* __restrict__ thr,
                          float* __restrict__ out) {
  const int i = blockIdx.x * blockDim.x + threadIdx.x;
  const int b = i >> 9;
  const int o = i & (OUT_F - 1);
  const float bt = beta[o];
  const float th = thr[o];
  float m = 0.0f;
  for (int t = 0; t < T_STEPS; ++t) {
    const size_t idx = (size_t)(t * BATCH + b) * OUT_F + o;
    m = m - bt + cur2[idx];
    const float s = (m > th) ? 1.0f : 0.0f;
    m -= s * th;
    out[idx] = s;
  }
}

// ---------------- launch ----------------
extern "C" void kernel_launch(void* const* d_in, const int* in_sizes, int n_in,
                              void* d_out, int out_size, void* d_ws, size_t ws_size,
                              hipStream_t stream) {
  const float* x        = (const float*)d_in[0];
  const float* w1       = (const float*)d_in[1];
  const float* w2       = (const float*)d_in[2];
  const float* b2       = (const float*)d_in[3];
  const float* beta_lsm = (const float*)d_in[4];
  const float* thr_lsm  = (const float*)d_in[5];
  const float* beta_ro  = (const float*)d_in[6];
  const float* thr_ro   = (const float*)d_in[7];
  float* out = (float*)d_out;

  char* ws = (char*)d_ws;
  size_t off = 0;
  auto alloc = [&](size_t bytes) -> char* {
    char* p = ws + off;
    off += (bytes + 255) & ~(size_t)255;
    return p;
  };
  __hip_bfloat16* w1hi = (__hip_bfloat16*)alloc((size_t)HID * TOTAL * 2);
  __hip_bfloat16* w1lo = (__hip_bfloat16*)alloc((size_t)HID * TOTAL * 2);
  __hip_bfloat16* xb   = (__hip_bfloat16*)alloc((size_t)T_STEPS * BATCH * IN_F * 2);
  __hip_bfloat16* spk  = (__hip_bfloat16*)alloc((size_t)(T_STEPS + 1) * BATCH * HID * 2);
  __hip_bfloat16* w2hi = (__hip_bfloat16*)alloc((size_t)OUT_F * HID * 2);
  __hip_bfloat16* w2lo = (__hip_bfloat16*)alloc((size_t)OUT_F * HID * 2);
  float* mem1 = (float*)alloc((size_t)BATCH * HID * 4);
  // part ([KSPL][B][HID] f32, 8MB) aliases cur2 (16.8MB): disjoint lifetimes
  // (part: step phase only; cur2: readout phase only).
  float* cur2 = (float*)alloc((size_t)T_STEPS * BATCH * OUT_F * 4);
  float* part = cur2;

  // prep
  {
    int n4 = HID * TOTAL / 4;
    k_cvt_split<<<(n4 + 255) / 256, 256, 0, stream>>>(w1, w1hi, w1lo, n4);
  }
  {
    int n4 = OUT_F * HID / 4;
    k_cvt_split<<<(n4 + 255) / 256, 256, 0, stream>>>(w2, w2hi, w2lo, n4);
  }
  {
    int n = T_STEPS * BATCH * IN_F;
    k_cvt_x<<<(n + 255) / 256, 256, 0, stream>>>(x, xb, n);
  }
  {
    int n = BATCH * HID;
    k_zero<<<(n + 255) / 256, 256, 0, stream>>>(mem1, (ushort*)spk, n);
  }

  // sequential reservoir steps: K-split GEMM (2 blocks/CU) + fused reduce/LIF
  for (int t = 0; t < T_STEPS; ++t) {
    k_fc1<<<NCH * KSPL, 256, 0, stream>>>(t, xb, spk, w1hi, w1lo, part);
    k_fc1_red<<<BATCH * HID / (256 * 4), 256, 0, stream>>>(
        part, mem1, beta_lsm, thr_lsm,
        (ushort*)(spk + (size_t)(t + 1) * BATCH * HID));
  }

  // readout
  k_ro_gemm<<<(T_STEPS * BATCH / 64) * (OUT_F / 64), 256, 0, stream>>>(
      spk + (size_t)BATCH * HID, w2hi, w2lo, b2, cur2);
  k_ro_scan<<<(BATCH * OUT_F) / 256, 256, 0, stream>>>(cur2, beta_ro, thr_ro, out);
}